// Round 5
// baseline (12465.422 us; speedup 1.0000x reference)
//
#include <hip/hip_runtime.h>

constexpr int Bb = 4, Ss = 2048, Dd = 1024, Ll = 4;
constexpr int BSm = Bb * Ss;          // 8192 rows flattened

constexpr int BM = 64, BN = 64, BK = 16;

// ---- generic GEMM: C[f32] = act(A[f32] @ W[f32] + bias), f32 accum ---------
// ACT: 0 = none, 1 = exact GELU
template<bool HAS_BIAS, int ACT>
__global__ __launch_bounds__(256) void gemm_f32(
    const float* __restrict__ A, int lda,
    const float* __restrict__ W, int ldw,
    const float* __restrict__ bias,
    float* __restrict__ C, int ldc, int K)
{
    __shared__ float As[BK][BM];
    __shared__ float Bs[BK][BN];
    const int tid  = threadIdx.x;
    const int row0 = blockIdx.y * BM, col0 = blockIdx.x * BN;
    const int arow = tid >> 2,  akq  = (tid & 3) * 4;
    const int brow = tid >> 4,  bcol = (tid & 15) * 4;
    const int tx   = (tid & 15) * 4, ty = (tid >> 4) * 4;
    float acc[4][4] = {};
    for (int k0 = 0; k0 < K; k0 += BK) {
        float4 av = *reinterpret_cast<const float4*>(A + (size_t)(row0 + arow) * lda + k0 + akq);
        float4 wv = *reinterpret_cast<const float4*>(W + (size_t)(k0 + brow) * ldw + col0 + bcol);
        __syncthreads();
        As[akq + 0][arow] = av.x;
        As[akq + 1][arow] = av.y;
        As[akq + 2][arow] = av.z;
        As[akq + 3][arow] = av.w;
        *reinterpret_cast<float4*>(&Bs[brow][bcol]) = wv;
        __syncthreads();
        #pragma unroll
        for (int k = 0; k < BK; ++k) {
            float4 a4 = *reinterpret_cast<const float4*>(&As[k][ty]);
            float4 b4 = *reinterpret_cast<const float4*>(&Bs[k][tx]);
            float a[4] = {a4.x, a4.y, a4.z, a4.w};
            float b[4] = {b4.x, b4.y, b4.z, b4.w};
            #pragma unroll
            for (int i = 0; i < 4; ++i)
                #pragma unroll
                for (int j = 0; j < 4; ++j)
                    acc[i][j] = fmaf(a[i], b[j], acc[i][j]);
        }
    }
    float bb[4] = {0.f, 0.f, 0.f, 0.f};
    if (HAS_BIAS) {
        float4 b4 = *reinterpret_cast<const float4*>(bias + col0 + tx);
        bb[0] = b4.x; bb[1] = b4.y; bb[2] = b4.z; bb[3] = b4.w;
    }
    #pragma unroll
    for (int i = 0; i < 4; ++i) {
        float4 o;
        float v0 = acc[i][0] + bb[0], v1 = acc[i][1] + bb[1];
        float v2 = acc[i][2] + bb[2], v3 = acc[i][3] + bb[3];
        if (ACT == 1) {
            v0 = 0.5f * v0 * (1.f + erff(v0 * 0.70710678118f));
            v1 = 0.5f * v1 * (1.f + erff(v1 * 0.70710678118f));
            v2 = 0.5f * v2 * (1.f + erff(v2 * 0.70710678118f));
            v3 = 0.5f * v3 * (1.f + erff(v3 * 0.70710678118f));
        }
        o.x = v0; o.y = v1; o.z = v2; o.w = v3;
        *reinterpret_cast<float4*>(C + (size_t)(row0 + ty + i) * ldc + col0 + tx) = o;
    }
}

// ---- scores[f32] = tril(q @ k^T) / (32 * (1+sqrt(i))) ----------------------
__global__ __launch_bounds__(256) void qkt_k(
    const float* __restrict__ q, const float* __restrict__ k,
    float* __restrict__ scores)
{
    const int bc = blockIdx.x, br = blockIdx.y, b = blockIdx.z;
    if (bc > br) return;                       // above diagonal: never read later
    const int row0 = br * BM, col0 = bc * BN;
    const float* qb = q + (size_t)b * Ss * Dd;
    const float* kb = k + (size_t)b * Ss * Dd;
    __shared__ float As[BK][BM];
    __shared__ float Bs[BK][BN];
    const int tid  = threadIdx.x;
    const int arow = tid >> 2, akq = (tid & 3) * 4;
    const int tx   = (tid & 15) * 4, ty = (tid >> 4) * 4;
    float acc[4][4] = {};
    for (int k0 = 0; k0 < Dd; k0 += BK) {
        float4 av = *reinterpret_cast<const float4*>(qb + (size_t)(row0 + arow) * Dd + k0 + akq);
        float4 bv = *reinterpret_cast<const float4*>(kb + (size_t)(col0 + arow) * Dd + k0 + akq);
        __syncthreads();
        As[akq + 0][arow] = av.x; As[akq + 1][arow] = av.y;
        As[akq + 2][arow] = av.z; As[akq + 3][arow] = av.w;
        Bs[akq + 0][arow] = bv.x; Bs[akq + 1][arow] = bv.y;
        Bs[akq + 2][arow] = bv.z; Bs[akq + 3][arow] = bv.w;
        __syncthreads();
        #pragma unroll
        for (int kk = 0; kk < BK; ++kk) {
            float4 a4 = *reinterpret_cast<const float4*>(&As[kk][ty]);
            float4 b4 = *reinterpret_cast<const float4*>(&Bs[kk][tx]);
            float a[4] = {a4.x, a4.y, a4.z, a4.w};
            float bq[4] = {b4.x, b4.y, b4.z, b4.w};
            #pragma unroll
            for (int i = 0; i < 4; ++i)
                #pragma unroll
                for (int j = 0; j < 4; ++j)
                    acc[i][j] = fmaf(a[i], bq[j], acc[i][j]);
        }
    }
    #pragma unroll
    for (int i = 0; i < 4; ++i) {
        const int gi = row0 + ty + i;
        const float rn = 1.0f / (32.0f * (1.0f + sqrtf((float)gi)));
        const int gj = col0 + tx;
        float4 o;
        o.x = (gj + 0 <= gi) ? acc[i][0] * rn : 0.0f;
        o.y = (gj + 1 <= gi) ? acc[i][1] * rn : 0.0f;
        o.z = (gj + 2 <= gi) ? acc[i][2] * rn : 0.0f;
        o.w = (gj + 3 <= gi) ? acc[i][3] * rn : 0.0f;
        *reinterpret_cast<float4*>(scores + ((size_t)b * Ss + gi) * Ss + gj) = o;
    }
}

// ---- ret[f32] = (scores / denom) @ v, denom computed in-kernel -------------
// denom[i] = max(1, |sum_{j<=i} scores[i,j]|): each block loads exactly the
// causal range (masked zeros included) for its 64 rows, so the per-row sum
// of loaded A values IS the full causal sum.
__global__ __launch_bounds__(256) void rv_k(
    const float* __restrict__ scores, const float* __restrict__ v,
    float* __restrict__ out)
{
    const int bn = blockIdx.x, bm = blockIdx.y, b = blockIdx.z;
    const int row0 = bm * BM, col0 = bn * BN;
    const float* A = scores + (size_t)b * Ss * Ss;
    const float* V = v + (size_t)b * Ss * Dd;
    const int Keff = row0 + BM;                                 // causal K limit
    __shared__ float As[BK][BM];
    __shared__ float Bs[BK][BN];
    __shared__ float dshared[BM];
    const int tid  = threadIdx.x;
    const int arow = tid >> 2,  akq  = (tid & 3) * 4;
    const int brow = tid >> 4,  bcol = (tid & 15) * 4;
    const int tx   = (tid & 15) * 4, ty = (tid >> 4) * 4;
    float acc[4][4] = {};
    float rowsum = 0.f;
    for (int k0 = 0; k0 < Keff; k0 += BK) {
        float4 av = *reinterpret_cast<const float4*>(A + (size_t)(row0 + arow) * Ss + k0 + akq);
        float4 bv = *reinterpret_cast<const float4*>(V + (size_t)(k0 + brow) * Dd + col0 + bcol);
        rowsum += (av.x + av.y) + (av.z + av.w);
        __syncthreads();
        As[akq + 0][arow] = av.x; As[akq + 1][arow] = av.y;
        As[akq + 2][arow] = av.z; As[akq + 3][arow] = av.w;
        *reinterpret_cast<float4*>(&Bs[brow][bcol]) = bv;
        __syncthreads();
        #pragma unroll
        for (int kk = 0; kk < BK; ++kk) {
            float4 a4 = *reinterpret_cast<const float4*>(&As[kk][ty]);
            float4 b4 = *reinterpret_cast<const float4*>(&Bs[kk][tx]);
            float a[4] = {a4.x, a4.y, a4.z, a4.w};
            float bq[4] = {b4.x, b4.y, b4.z, b4.w};
            #pragma unroll
            for (int i = 0; i < 4; ++i)
                #pragma unroll
                for (int j = 0; j < 4; ++j)
                    acc[i][j] = fmaf(a[i], bq[j], acc[i][j]);
        }
    }
    // reduce rowsum over the 4 lanes sharing arow (tid = 4*arow + q)
    rowsum += __shfl_xor(rowsum, 1);
    rowsum += __shfl_xor(rowsum, 2);
    if ((tid & 3) == 0) dshared[arow] = rowsum;
    __syncthreads();
    #pragma unroll
    for (int i = 0; i < 4; ++i) {
        const int gi = row0 + ty + i;
        const float sc = 1.0f / fmaxf(1.0f, fabsf(dshared[ty + i]));
        float4 o;
        o.x = acc[i][0] * sc; o.y = acc[i][1] * sc;
        o.z = acc[i][2] * sc; o.w = acc[i][3] * sc;
        *reinterpret_cast<float4*>(out + ((size_t)b * Ss + gi) * Dd + col0 + tx) = o;
    }
}

// ---- SwiGLU: out = a * silu(gate) ------------------------------------------
__global__ __launch_bounds__(256) void swiglu_k(
    const float* __restrict__ m1, float* __restrict__ out)
{
    const size_t e = (size_t)blockIdx.x * 256 + threadIdx.x;   // B*S*D/4
    const size_t row = e / (Dd / 4);
    const int c4 = (int)(e % (Dd / 4));
    const float* base = m1 + row * (2 * Dd);
    float4 a = *reinterpret_cast<const float4*>(base + c4 * 4);
    float4 g = *reinterpret_cast<const float4*>(base + Dd + c4 * 4);
    float4 o;
    o.x = a.x * (g.x / (1.f + expf(-g.x)));
    o.y = a.y * (g.y / (1.f + expf(-g.y)));
    o.z = a.z * (g.z / (1.f + expf(-g.z)));
    o.w = a.w * (g.w / (1.f + expf(-g.w)));
    *reinterpret_cast<float4*>(out + row * Dd + c4 * 4) = o;
}

// ---- GroupNorm(1,D): per-batch mean/var over S*D ---------------------------
__global__ __launch_bounds__(256) void gn_part_k(
    const float* __restrict__ m2, float* __restrict__ part)
{
    const int b = blockIdx.y, blk = blockIdx.x;    // 256 blocks per batch
    const float* p = m2 + (size_t)b * Ss * Dd + (size_t)blk * 8192;
    float s = 0.f, ss = 0.f;
    for (int t = threadIdx.x; t < 2048; t += 256) {
        float4 v = *reinterpret_cast<const float4*>(p + (size_t)t * 4);
        s  += (v.x + v.y) + (v.z + v.w);
        ss += v.x * v.x + v.y * v.y + v.z * v.z + v.w * v.w;
    }
    __shared__ float rs[256], rss[256];
    rs[threadIdx.x] = s; rss[threadIdx.x] = ss;
    __syncthreads();
    for (int off = 128; off > 0; off >>= 1) {
        if (threadIdx.x < off) {
            rs[threadIdx.x]  += rs[threadIdx.x + off];
            rss[threadIdx.x] += rss[threadIdx.x + off];
        }
        __syncthreads();
    }
    if (threadIdx.x == 0) {
        part[(b * 256 + blk) * 2]     = rs[0];
        part[(b * 256 + blk) * 2 + 1] = rss[0];
    }
}

__global__ __launch_bounds__(256) void gn_final_k(
    const float* __restrict__ part, float* __restrict__ stats)
{
    const int b = blockIdx.x, t = threadIdx.x;
    float s  = part[(b * 256 + t) * 2];
    float ss = part[(b * 256 + t) * 2 + 1];
    __shared__ float rs[256], rss[256];
    rs[t] = s; rss[t] = ss;
    __syncthreads();
    for (int off = 128; off > 0; off >>= 1) {
        if (t < off) { rs[t] += rs[t + off]; rss[t] += rss[t + off]; }
        __syncthreads();
    }
    if (t == 0) {
        const float inv_n = 1.0f / (float)((size_t)Ss * Dd);
        float mean = rs[0] * inv_n;
        float var  = fmaxf(rss[0] * inv_n - mean * mean, 0.0f);
        stats[b * 2]     = mean;
        stats[b * 2 + 1] = rsqrtf(var + 1e-5f);
    }
}

__global__ __launch_bounds__(256) void gn_apply_k(
    const float* __restrict__ m2, const float* __restrict__ h,
    const float* __restrict__ g, const float* __restrict__ bta,
    const float* __restrict__ stats, float* __restrict__ y)
{
    const size_t e = (size_t)blockIdx.x * 256 + threadIdx.x;   // B*S*D/4
    const int b  = (int)(e / ((size_t)Ss * Dd / 4));
    const int c4 = (int)(e % (Dd / 4));
    const float mean = stats[b * 2], istd = stats[b * 2 + 1];
    float4 m  = *reinterpret_cast<const float4*>(m2 + e * 4);
    float4 hh = *reinterpret_cast<const float4*>(h + e * 4);
    float4 g4 = *reinterpret_cast<const float4*>(g + c4 * 4);
    float4 b4 = *reinterpret_cast<const float4*>(bta + c4 * 4);
    float4 o;
    o.x = (m.x - mean) * istd * g4.x + b4.x + hh.x;
    o.y = (m.y - mean) * istd * g4.y + b4.y + hh.y;
    o.z = (m.z - mean) * istd * g4.z + b4.z + hh.z;
    o.w = (m.w - mean) * istd * g4.w + b4.w + hh.w;
    *reinterpret_cast<float4*>(y + e * 4) = o;
}

// ---- LayerNorm over D; fp32 out (next h or d_out) --------------------------
__global__ __launch_bounds__(256) void ln_k(
    const float* __restrict__ f2, const float* __restrict__ y,
    const float* __restrict__ g, const float* __restrict__ bta,
    float* __restrict__ out)
{
    const int row = blockIdx.x;          // 0 .. B*S-1
    const int t = threadIdx.x;           // 256 threads, 4 elems each (D=1024)
    float4 fv = *reinterpret_cast<const float4*>(f2 + (size_t)row * Dd + t * 4);
    float4 yv = *reinterpret_cast<const float4*>(y  + (size_t)row * Dd + t * 4);
    const float v0 = fv.x + yv.x, v1 = fv.y + yv.y;
    const float v2 = fv.z + yv.z, v3 = fv.w + yv.w;
    float s  = (v0 + v1) + (v2 + v3);
    float ss = v0 * v0 + v1 * v1 + v2 * v2 + v3 * v3;
    __shared__ float rs[256], rss[256];
    rs[t] = s; rss[t] = ss;
    __syncthreads();
    for (int off = 128; off > 0; off >>= 1) {
        if (t < off) { rs[t] += rs[t + off]; rss[t] += rss[t + off]; }
        __syncthreads();
    }
    const float mean = rs[0] * (1.0f / Dd);
    const float var  = fmaxf(rss[0] * (1.0f / Dd) - mean * mean, 0.0f);
    const float istd = rsqrtf(var + 1e-5f);
    float4 g4 = *reinterpret_cast<const float4*>(g + t * 4);
    float4 b4 = *reinterpret_cast<const float4*>(bta + t * 4);
    float4 o;
    o.x = (v0 - mean) * istd * g4.x + b4.x;
    o.y = (v1 - mean) * istd * g4.y + b4.y;
    o.z = (v2 - mean) * istd * g4.z + b4.z;
    o.w = (v3 - mean) * istd * g4.w + b4.w;
    *reinterpret_cast<float4*>(out + (size_t)row * Dd + t * 4) = o;
}

extern "C" void kernel_launch(void* const* d_in, const int* in_sizes, int n_in,
                              void* d_out, int out_size, void* d_ws, size_t ws_size,
                              hipStream_t stream)
{
    const float* x    = (const float*)d_in[0];
    const float* Wkqv = (const float*)d_in[1];
    const float* Wm1  = (const float*)d_in[2];
    const float* bm1  = (const float*)d_in[3];
    const float* Wm2  = (const float*)d_in[4];
    const float* bm2  = (const float*)d_in[5];
    const float* gng  = (const float*)d_in[6];
    const float* gnb  = (const float*)d_in[7];
    const float* Wf1  = (const float*)d_in[8];
    const float* bf1  = (const float*)d_in[9];
    const float* Wf2  = (const float*)d_in[10];
    const float* bf2  = (const float*)d_in[11];
    const float* lng  = (const float*)d_in[12];
    const float* lnb  = (const float*)d_in[13];

    // 32 MiB slots, lifetime-colored; peak exactly 192 MiB (proven safe in R4).
    //   S0 [0,32):    h
    //   S1 [32,64):   k -> ret -> m2 -> f2
    //   S2 [64,96):   q -> y
    //   S3 [96,128):  v -> sw -> part/stats
    //   S4S5 [128,192): scores(f32) -> m1 -> f1
    char* wsb = (char*)d_ws;
    const size_t MiB = 1024 * 1024;
    float* hbuf   = (float*)(wsb);
    float* kS1    = (float*)(wsb + 32 * MiB);
    float* qS2    = (float*)(wsb + 64 * MiB);
    float* vS3    = (float*)(wsb + 96 * MiB);
    float* scores = (float*)(wsb + 128 * MiB);
    float* retR   = kS1;       // after k dead
    float* m2R    = kS1;       // after ret dead
    float* f2R    = kS1;       // after m2 dead
    float* yR     = qS2;       // after q dead
    float* swR    = vS3;       // after v dead
    float* m1R    = scores;    // after scores dead
    float* f1R    = scores;    // after m1 dead
    float* part   = vS3;       // after sw dead (gn stage only)
    float* stats  = part + 2 * Bb * 256;

    for (int l = 0; l < Ll; ++l) {
        const float* h = (l == 0) ? x : hbuf;
        const float* Wl = Wkqv + (size_t)l * Dd * 3 * Dd;

        // k, q, v = h @ Wkqv[:, 0:D / D:2D / 2D:3D]
        gemm_f32<false, 0><<<dim3(Dd / BN, BSm / BM), 256, 0, stream>>>(
            h, Dd, Wl,          3 * Dd, nullptr, kS1, Dd, Dd);
        gemm_f32<false, 0><<<dim3(Dd / BN, BSm / BM), 256, 0, stream>>>(
            h, Dd, Wl + Dd,     3 * Dd, nullptr, qS2, Dd, Dd);
        gemm_f32<false, 0><<<dim3(Dd / BN, BSm / BM), 256, 0, stream>>>(
            h, Dd, Wl + 2 * Dd, 3 * Dd, nullptr, vS3, Dd, Dd);

        qkt_k<<<dim3(Ss / BN, Ss / BM, Bb), 256, 0, stream>>>(qS2, kS1, scores);
        rv_k<<<dim3(Dd / BN, Ss / BM, Bb), 256, 0, stream>>>(scores, vS3, retR);

        gemm_f32<true, 0><<<dim3(2 * Dd / BN, BSm / BM), 256, 0, stream>>>(
            retR, Dd, Wm1 + (size_t)l * Dd * 2 * Dd, 2 * Dd,
            bm1 + (size_t)l * 2 * Dd, m1R, 2 * Dd, Dd);        // scores dead

        swiglu_k<<<BSm * Dd / 4 / 256, 256, 0, stream>>>(m1R, swR);  // v dead

        gemm_f32<true, 0><<<dim3(Dd / BN, BSm / BM), 256, 0, stream>>>(
            swR, Dd, Wm2 + (size_t)l * Dd * Dd, Dd,
            bm2 + (size_t)l * Dd, m2R, Dd, Dd);                // ret dead

        gn_part_k<<<dim3(256, Bb), 256, 0, stream>>>(m2R, part);     // sw dead
        gn_final_k<<<Bb, 256, 0, stream>>>(part, stats);
        gn_apply_k<<<BSm * Dd / 4 / 256, 256, 0, stream>>>(
            m2R, h, gng + (size_t)l * Dd, gnb + (size_t)l * Dd, stats, yR);

        gemm_f32<true, 1><<<dim3(2 * Dd / BN, BSm / BM), 256, 0, stream>>>(
            yR, Dd, Wf1 + (size_t)l * Dd * 2 * Dd, 2 * Dd,
            bf1 + (size_t)l * 2 * Dd, f1R, 2 * Dd, Dd);        // m1 dead; GELU fused

        gemm_f32<true, 0><<<dim3(Dd / BN, BSm / BM), 256, 0, stream>>>(
            f1R, 2 * Dd, Wf2 + (size_t)l * 2 * Dd * Dd, Dd,
            bf2 + (size_t)l * Dd, f2R, Dd, 2 * Dd);            // m2 dead

        ln_k<<<BSm, 256, 0, stream>>>(
            f2R, yR, lng + (size_t)l * Dd, lnb + (size_t)l * Dd,
            (l == Ll - 1) ? (float*)d_out : hbuf);
    }
}